// Round 9
// baseline (251.755 us; speedup 1.0000x reference)
//
#include <hip/hip_runtime.h>
#include <hip/hip_bf16.h>

typedef __attribute__((ext_vector_type(8))) short short8;
typedef __attribute__((ext_vector_type(4))) short short4_;
typedef __attribute__((ext_vector_type(4))) float float4_;
typedef __attribute__((ext_vector_type(2))) unsigned int uint2_;
typedef __attribute__((ext_vector_type(4))) unsigned int uint4_;

#define CH 64
#define HH 256
#define WW 256
#define HW (HH*WW)
#define CHW (CH*HW)

#define TW 16
#define TH 8
#define XPW 20
#define XPH 12
#define NXP 240        // x/qkv halo set (halo 2)
#define OPW 18
#define OPH 10
#define NOP 180        // out1 set (halo 1)

#define XLS 72         // x staging stride (144 B, round-4/6 verified banks)
#define KQ2 40         // k stride (80 B): dot reads step np by +1 per lane ->
                       // banks +20: spread (verified R4-R8 pattern)
#define VS  32         // vbuf stride + granule swizzle (R5-R8)
#define O1S 64         // o1b stride + granule swizzle ^pix&7 (R5-R8)
#define TBS 132        // tb2 row stride (floats): [64ch][132]

// LDS regions (shorts), SMEM 19200 = 38400 B -> 4 blocks/CU:
//  xls   [0, 17280)                      (staging only)
//  kA    [0, 9600) ; kB [9600, 19200)    (QK rounds, double-buffered)
//  vbuf  [0, 7680)                       (V rounds; kA dead)
//  o1b   [7680, 19200)                   (PV/conv; kB dead)
//  tb2   [0, 16896)  floats [64][132]    (epilogue; all dead)
#define KB_OFF  9600
#define O1_OFF  7680
#define SMEM_SHORTS 19200

// ws layout: wsq bf16 [0,24576) ; wsm bf16 [24576, 98304)
#define WSQ_SHORTS 12288
#define WSM_SHORTS 36864

__device__ __forceinline__ float blo(unsigned u) {
    return __uint_as_float(u << 16);
}
__device__ __forceinline__ float bhi(unsigned u) {
    return __uint_as_float(u & 0xffff0000u);
}
__device__ __forceinline__ short f2bs(float f) {
    __hip_bfloat16 h = __float2bfloat16(f);
    short s; __builtin_memcpy(&s, &h, 2); return s;
}
__device__ __forceinline__ unsigned pack2(float a, float b) {
    return (unsigned)(unsigned short)f2bs(a) |
           ((unsigned)(unsigned short)f2bs(b) << 16);
}

// xls swizzled index: channel c of halo pixel pix
__device__ __forceinline__ int xls_idx(int pix, int c) {
    int g = ((c >> 3) ^ ((pix >> 2) & 7));
    return pix * XLS + g * 8 + (c & 7);
}
// o1b swizzled index
__device__ __forceinline__ int o1_idx(int pix, int c) {
    int g = (((c >> 3) ^ pix) & 7);
    return pix * O1S + g * 8 + (c & 7);
}
// vbuf swizzle key
__device__ __forceinline__ int vswz(int p) {
    return (p ^ (p >> 2)) & 3;
}

#if defined(__has_builtin)
#if __has_builtin(__builtin_amdgcn_fdot2_f32_bf16)
#define HAS_BF16_DOT2 1
#endif
#endif
#ifdef HAS_BF16_DOT2
typedef __bf16 bf16x2 __attribute__((ext_vector_type(2)));
__device__ __forceinline__ float dot2acc(unsigned a, unsigned b, float acc) {
    return __builtin_amdgcn_fdot2_f32_bf16(__builtin_bit_cast(bf16x2, a),
                                           __builtin_bit_cast(bf16x2, b),
                                           acc, false);
}
#else
__device__ __forceinline__ float dot2acc(unsigned a, unsigned b, float acc) {
    acc += blo(a) * blo(b);
    acc += bhi(a) * bhi(b);
    return acc;
}
#endif

// ---- prep: pack wqkv/wmlp to bf16 in exact fragment order -------------------
__global__ void prep_pack(const float* __restrict__ wqkv,
                          const float* __restrict__ wmlp,
                          short* __restrict__ wsq, short* __restrict__ wsm) {
    int idx = blockIdx.x * blockDim.x + threadIdx.x;
    int stride = gridDim.x * blockDim.x;
    for (int e = idx; e < WSQ_SHORTS; e += stride) {
        int j = e & 7, lane = (e >> 3) & 63;
        int ks = (e >> 9) & 1, q16 = (e >> 10) & 3, sec = e >> 12;
        int row = sec*64 + q16*16 + (lane & 15);
        int kk  = ks*32 + (lane >> 4)*8 + j;
        wsq[e] = f2bs(wqkv[(size_t)row*64 + kk]);
    }
    for (int e = idx; e < WSM_SHORTS; e += stride) {
        int j = e & 7, lane = (e >> 3) & 63;
        int rest = e >> 9;            // 0..71
        int nt = rest / 18, ks = rest % 18;
        int o   = nt*16 + (lane & 15);
        int cin = (ks & 1)*32 + (lane >> 4)*8 + j;
        int tap = ks >> 1;
        wsm[e] = f2bs(wmlp[(size_t)o*576 + cin*9 + tap]);
    }
}

// ---- fused kernel -----------------------------------------------------------
// Round-9: 13 -> 10 barriers. q stays in registers (thread t owns halo pixel
// t at gemm tile i=quad under swapped operands); partial dots per quad +
// shfl_xor(32/16) butterfly; kbuf double-buffered so dot(rr) overlaps
// gemm(rr+1) in one phase (cross-wave MFMA/VALU overlap, no barrier between).
// Epilogue: single [ch][132] tbuf, all-b128.
__global__ __launch_bounds__(256, 3) void fused_mfma(
    const float* __restrict__ x, const short* __restrict__ wsq,
    const float* __restrict__ bqkv, const short* __restrict__ wsm,
    float* __restrict__ out)
{
    __shared__ __align__(16) short smem[SMEM_SHORTS];
    short* xls  = smem;
    short* kA   = smem;                              // [240][40]
    short* kB   = smem + KB_OFF;                     // [240][40]
    short* vbuf = smem;                              // [240][32]sw
    short* o1b  = smem + O1_OFF;                     // [180][64]sw
    float* tb2  = (float*)smem;                      // [64][132]

    const int t    = threadIdx.x;
    const int w    = t >> 6;
    const int lane = t & 63;
    const int n16  = lane & 15;
    const int quad = lane >> 4;

    // XCD-chunk swizzle (round-2 verified). 2048 % 8 == 0 -> bijective.
    const int d   = blockIdx.x + (blockIdx.y << 4) + (blockIdx.z << 9);
    const int nn  = ((d & 7) << 8) | (d >> 3);
    const int b   = nn >> 9;
    const int rem = nn & 511;
    const int gy0 = (rem >> 4) * TH;
    const int gx0 = (rem & 15) * TW;
    const float* xb = x + (size_t)b * CHW;

    // ---- phase X: stage x halo into LDS bf16 (R4-verified pattern)
    for (int slot = t; slot < 32*12*6; slot += 256) {
        int s6 = slot % 6, y = (slot / 6) % 12, c2 = slot / 72;
        int c  = c2 * 2;
        int gy = gy0 - 2 + y;
        int gxb = gx0 - 4 + s6*4;
        float v0[4], v1[4];
        bool gyok = (unsigned)gy < HH;
        if (gyok && gxb >= 0 && gxb + 3 < WW) {
            float4_ f0 = *(const float4_*)(xb + (size_t)c*HW + gy*WW + gxb);
            float4_ f1 = *(const float4_*)(xb + (size_t)(c+1)*HW + gy*WW + gxb);
            #pragma unroll
            for (int i = 0; i < 4; ++i) { v0[i] = f0[i]; v1[i] = f1[i]; }
        } else {
            #pragma unroll
            for (int i = 0; i < 4; ++i) {
                int gx = gxb + i;
                bool ok = gyok && (unsigned)gx < WW;
                v0[i] = ok ? xb[(size_t)c*HW + gy*WW + gx] : 0.f;
                v1[i] = ok ? xb[(size_t)(c+1)*HW + gy*WW + gx] : 0.f;
            }
        }
        #pragma unroll
        for (int i = 0; i < 4; ++i) {
            int pxc = s6*4 + i - 2;
            if ((unsigned)pxc < XPW)
                *(unsigned*)&xls[xls_idx(y*XPW + pxc, c)] = pack2(v0[i], v1[i]);
        }
    }
    __syncthreads();                                             // |1|

    // per-tile OOB mask: bit i -> halo pixel (w*4+i)*16 + n16
    unsigned okb = 0;
    #pragma unroll
    for (int i = 0; i < 4; ++i) {
        int p = (w*4 + i)*16 + n16;
        if (p < NXP) {
            int gy = gy0 - 2 + p / XPW, gx = gx0 - 2 + p % XPW;
            if (((unsigned)gy < HH) && ((unsigned)gx < WW))
                okb |= 1u << i;
        }
    }

    // ---- A-frags + residual capture. Attention pixel of thread t = halo
    // pixel t (t<240): under swapped operands t's q lives in its own regs.
    short8 afr[4][2];
    #pragma unroll
    for (int i = 0; i < 4; ++i) {
        int p = (w*4 + i)*16 + n16;
        int pr = (p < NXP) ? p : 0;
        #pragma unroll
        for (int ks = 0; ks < 2; ++ks)
            afr[i][ks] = *(const short8*)&xls[xls_idx(pr, ks*32 + quad*8)];
    }
    const int hpy = t / XPW, hpx = t % XPW;
    const bool inter = (t < NXP) &&
                       ((unsigned)(hpy - 1) < (unsigned)OPH) &&
                       ((unsigned)(hpx - 1) < (unsigned)OPW);
    const int ogy = gy0 - 2 + hpy, ogx = gx0 - 2 + hpx;
    const bool oin = inter && ((unsigned)ogy < HH) && ((unsigned)ogx < WW);
    const int opix = (hpy - 1)*OPW + (hpx - 1);
    short8 resi[8];
    if (inter) {
        #pragma unroll
        for (int g = 0; g < 8; ++g)
            resi[g] = *(const short8*)&xls[xls_idx(t, g*8)];
    }
    __syncthreads();                                             // |2|

    auto wload = [&](int sec, int q16, int ks) -> short8 {
        return *(const short8*)&wsq[(((sec*4 + q16)*2 + ks) << 9) + lane*8];
    };
    auto bload4 = [&](int base) -> float4_ {
        return *(const float4_*)&bqkv[base + quad*4];
    };

    unsigned qp[4][4];     // this round's q: tile i, 8ch packed (4 uints)
    auto gemm_qreg = [&](short8 w0, short8 w1, float4_ b4, int half) {
        #pragma unroll
        for (int i = 0; i < 4; ++i) {
            float4_ c = {0.f,0.f,0.f,0.f};
            c = __builtin_amdgcn_mfma_f32_16x16x32_bf16(w0, afr[i][0], c, 0, 0, 0);
            c = __builtin_amdgcn_mfma_f32_16x16x32_bf16(w1, afr[i][1], c, 0, 0, 0);
            qp[i][half*2 + 0] = pack2(c[0] + b4[0], c[1] + b4[1]);
            qp[i][half*2 + 1] = pack2(c[2] + b4[2], c[3] + b4[3]);
        }
    };
    auto gemm_kbuf = [&](short8 w0, short8 w1, float4_ b4, short* dst, int coff) {
        #pragma unroll
        for (int i = 0; i < 4; ++i) {
            int p = (w*4 + i)*16 + n16;
            float4_ c = {0.f,0.f,0.f,0.f};
            c = __builtin_amdgcn_mfma_f32_16x16x32_bf16(w0, afr[i][0], c, 0, 0, 0);
            c = __builtin_amdgcn_mfma_f32_16x16x32_bf16(w1, afr[i][1], c, 0, 0, 0);
            if (p < NXP) {
                bool ok = (okb >> i) & 1u;
                short4_ s;
                #pragma unroll
                for (int r = 0; r < 4; ++r) s[r] = ok ? f2bs(c[r] + b4[r]) : (short)0;
                *(short4_*)&dst[p*KQ2 + coff + quad*4] = s;
            }
        }
    };
    auto gemm_vbuf = [&](short8 w0, short8 w1, float4_ b4, int coff) {
        #pragma unroll
        for (int i = 0; i < 4; ++i) {
            int p = (w*4 + i)*16 + n16;
            float4_ c = {0.f,0.f,0.f,0.f};
            c = __builtin_amdgcn_mfma_f32_16x16x32_bf16(w0, afr[i][0], c, 0, 0, 0);
            c = __builtin_amdgcn_mfma_f32_16x16x32_bf16(w1, afr[i][1], c, 0, 0, 0);
            if (p < NXP) {
                bool ok = (okb >> i) & 1u;
                short4_ s;
                #pragma unroll
                for (int r = 0; r < 4; ++r) s[r] = ok ? f2bs(c[r] + b4[r]) : (short)0;
                int cc = coff + quad*4;
                int idx = p*VS + ((((cc >> 3) ^ vswz(p)) & 3) << 3) + (cc & 7);
                *(short4_*)&vbuf[idx] = s;
            }
        }
    };

    float dots[9];
    #pragma unroll
    for (int n2 = 0; n2 < 9; ++n2) dots[n2] = 0.f;

    // partial dots over this thread's 8 q-channels for its 4 gemm pixels,
    // then butterfly-sum across quads; lane keeps pixel p_{i=quad} = t.
    const bool hi2 = (quad & 2) != 0, hi1 = (quad & 1) != 0;
    auto dot_partial = [&](const short* kb) {
        #pragma unroll
        for (int dy = 0; dy < 3; ++dy) {
            float P[4][3];
            #pragma unroll
            for (int i = 0; i < 4; ++i) {
                int pi = (w*4 + i)*16 + n16;
                #pragma unroll
                for (int dx = 0; dx < 3; ++dx) {
                    int np = pi + (dy - 1)*XPW + (dx - 1);
                    np = np < 0 ? 0 : (np > NXP-1 ? NXP-1 : np);   // med3 clamp
                    uint2_ k0 = *(const uint2_*)&kb[np*KQ2 + quad*4];
                    uint2_ k1 = *(const uint2_*)&kb[np*KQ2 + 16 + quad*4];
                    float s = 0.f;
                    s = dot2acc(qp[i][0], k0[0], s);
                    s = dot2acc(qp[i][1], k0[1], s);
                    s = dot2acc(qp[i][2], k1[0], s);
                    s = dot2acc(qp[i][3], k1[1], s);
                    P[i][dx] = s;
                }
            }
            #pragma unroll
            for (int dx = 0; dx < 3; ++dx) {
                // stage 1 (lane^32): keep the i-pair containing quad
                float own0 = hi2 ? P[2][dx] : P[0][dx];
                float own1 = hi2 ? P[3][dx] : P[1][dx];
                float snd0 = hi2 ? P[0][dx] : P[2][dx];
                float snd1 = hi2 ? P[1][dx] : P[3][dx];
                float S0 = own0 + __shfl_xor(snd0, 32);
                float S1 = own1 + __shfl_xor(snd1, 32);
                // stage 2 (lane^16): keep i == quad
                float own2 = hi1 ? S1 : S0;
                float snd2 = hi1 ? S0 : S1;
                dots[dy*3 + dx] += own2 + __shfl_xor(snd2, 16);
            }
        }
    };

    // ---- |3| gemm QK round 0 (q ch 0-31 -> regs, k ch 0-31 -> kA)
    {
        short8 a0 = wload(0,0,0), a1 = wload(0,0,1);
        short8 a2 = wload(0,1,0), a3 = wload(0,1,1);
        short8 k0 = wload(1,0,0), k1 = wload(1,0,1);
        short8 k2 = wload(1,1,0), k3 = wload(1,1,1);
        gemm_qreg(a0, a1, bload4(0), 0);
        gemm_qreg(a2, a3, bload4(16), 1);
        gemm_kbuf(k0, k1, bload4(64), kA, 0);
        gemm_kbuf(k2, k3, bload4(64+16), kA, 16);
    }
    __syncthreads();                                             // |3|

    // ---- |4| dot round 0 (kA) ; gemm QK round 1 -> kB (waves overlap)
    dot_partial(kA);
    {
        short8 a0 = wload(0,2,0), a1 = wload(0,2,1);
        short8 a2 = wload(0,3,0), a3 = wload(0,3,1);
        short8 k0 = wload(1,2,0), k1 = wload(1,2,1);
        short8 k2 = wload(1,3,0), k3 = wload(1,3,1);
        gemm_qreg(a0, a1, bload4(32), 0);
        gemm_qreg(a2, a3, bload4(48), 1);
        gemm_kbuf(k0, k1, bload4(64+32), kB, 0);
        gemm_kbuf(k2, k3, bload4(64+48), kB, 16);
    }
    __syncthreads();                                             // |4|

    // ---- |5| dot round 1 (kB) ; gemm V round 0 -> vbuf (kA region, dead)
    dot_partial(kB);
    {
        short8 v0 = wload(2,0,0), v1 = wload(2,0,1);
        short8 v2 = wload(2,1,0), v3 = wload(2,1,1);
        gemm_vbuf(v0, v1, bload4(128), 0);
        gemm_vbuf(v2, v3, bload4(128+16), 16);
    }
    __syncthreads();                                             // |5|

    // ---- softmax (registers)
    float attn[9];
    if (oin) {
        float mx = -1e30f;
        #pragma unroll
        for (int n2 = 0; n2 < 9; ++n2) { dots[n2] *= 0.125f; mx = fmaxf(mx, dots[n2]); }
        float se = 0.f;
        #pragma unroll
        for (int n2 = 0; n2 < 9; ++n2) { attn[n2] = __expf(dots[n2] - mx); se += attn[n2]; }
        float inv = 1.f / se;
        #pragma unroll
        for (int n2 = 0; n2 < 9; ++n2) attn[n2] *= inv;
    }

    // PV for one 32-ch v round -> o1b (kB region, dead after dot1)
    auto pv_round = [&](int rr2) {
        if (inter) {
            #pragma unroll
            for (int h2 = 0; h2 < 2; ++h2) {
                const int kg = rr2*2 + h2;
                short8 s0, s1;
                if (oin) {
                    float o1[16];
                    uint4_ r0 = __builtin_bit_cast(uint4_, resi[kg*2]);
                    uint4_ r1 = __builtin_bit_cast(uint4_, resi[kg*2 + 1]);
                    #pragma unroll
                    for (int j = 0; j < 4; ++j) {
                        o1[2*j]     = blo(r0[j]); o1[2*j + 1]     = bhi(r0[j]);
                        o1[8 + 2*j] = blo(r1[j]); o1[8 + 2*j + 1] = bhi(r1[j]);
                    }
                    #pragma unroll
                    for (int n2 = 0; n2 < 9; ++n2) {
                        float a = attn[n2];
                        int np = t + (n2/3 - 1)*XPW + (n2%3 - 1);
                        int sw = vswz(np);
                        uint4_ va = *(const uint4_*)&vbuf[np*VS + (((h2*2)   ^ sw) << 3)];
                        uint4_ vb = *(const uint4_*)&vbuf[np*VS + (((h2*2+1) ^ sw) << 3)];
                        #pragma unroll
                        for (int j = 0; j < 4; ++j) {
                            o1[2*j]         += a * blo(va[j]);
                            o1[2*j + 1]     += a * bhi(va[j]);
                            o1[8 + 2*j]     += a * blo(vb[j]);
                            o1[8 + 2*j + 1] += a * bhi(vb[j]);
                        }
                    }
                    #pragma unroll
                    for (int j = 0; j < 8; ++j) {
                        s0[j] = f2bs(o1[j]);
                        s1[j] = f2bs(o1[8 + j]);
                    }
                } else {
                    #pragma unroll
                    for (int j = 0; j < 8; ++j) { s0[j] = 0; s1[j] = 0; }
                }
                *(short8*)&o1b[o1_idx(opix, kg*16)]     = s0;
                *(short8*)&o1b[o1_idx(opix, kg*16 + 8)] = s1;
            }
        }
    };

    // ---- |6| PV round 0 (v ch 0-31)
    pv_round(0);
    __syncthreads();                                             // |6|

    // ---- |7| gemm V round 1 -> vbuf (overwrite)
    {
        short8 v0 = wload(2,2,0), v1 = wload(2,2,1);
        short8 v2 = wload(2,3,0), v3 = wload(2,3,1);
        gemm_vbuf(v0, v1, bload4(128+32), 0);
        gemm_vbuf(v2, v3, bload4(128+48), 16);
    }
    __syncthreads();                                             // |7|

    // ---- |8| PV round 1 (v ch 32-63)
    pv_round(1);
    __syncthreads();                                             // |8|

    // ---- 3x3 conv 64->64 as one MFMA burst (K=576 tap-major), B from ws
    float4_ acc[4][2];
    #pragma unroll
    for (int nt = 0; nt < 4; ++nt) {
        acc[nt][0] = (float4_){0.f,0.f,0.f,0.f};
        acc[nt][1] = (float4_){0.f,0.f,0.f,0.f};
    }
    const int mtc0 = w*2, mtc1 = w*2 + 1;
    for (int ks = 0; ks < 18; ++ks) {
        int tap = ks >> 1;
        int dy = tap/3 - 1, dx = tap%3 - 1;
        int cin0 = (ks & 1)*32 + quad*8;
        int pixA = (mtc0 + 1 + dy)*OPW + (n16 + 1 + dx);
        int pixB = (mtc1 + 1 + dy)*OPW + (n16 + 1 + dx);
        short8 a0 = *(const short8*)&o1b[o1_idx(pixA, cin0)];
        short8 a1 = *(const short8*)&o1b[o1_idx(pixB, cin0)];
        #pragma unroll
        for (int nt = 0; nt < 4; ++nt) {
            short8 bb = *(const short8*)&wsm[((nt*18 + ks) << 9) + lane*8];
            acc[nt][0] = __builtin_amdgcn_mfma_f32_16x16x32_bf16(a0, bb, acc[nt][0], 0, 0, 0);
            acc[nt][1] = __builtin_amdgcn_mfma_f32_16x16x32_bf16(a1, bb, acc[nt][1], 0, 0, 0);
        }
    }
    __syncthreads();                                             // |9|

    // ---- epilogue: single flipped tbuf [ch][132], all-b128
    #pragma unroll
    for (int nt = 0; nt < 4; ++nt)
        #pragma unroll
        for (int h = 0; h < 2; ++h) {
            int mtc = w*2 + h;
            float4_ rv;
            #pragma unroll
            for (int r = 0; r < 4; ++r) rv[r] = fmaxf(acc[nt][h][r], 0.f);
            *(float4_*)&tb2[(nt*16 + n16)*TBS + mtc*16 + quad*4] = rv;
        }
    __syncthreads();                                             // |10|
    #pragma unroll
    for (int k = 0; k < 8; ++k) {
        int unit = t + k*256;                  // 2048 units: ch(64) y(8) xg(4)
        int ch = unit >> 5, y = (unit >> 2) & 7, xg = unit & 3;
        float4_ v = *(const float4_*)&tb2[ch*TBS + y*16 + xg*4];
        *(float4_*)(out + (size_t)b*CHW + (size_t)ch*HW
                    + (size_t)(gy0 + y)*WW + (gx0 + xg*4)) = v;
    }
}

extern "C" void kernel_launch(void* const* d_in, const int* in_sizes, int n_in,
                              void* d_out, int out_size, void* d_ws, size_t ws_size,
                              hipStream_t stream) {
    const float* x    = (const float*)d_in[0];
    const float* wqkv = (const float*)d_in[1];
    const float* bqkv = (const float*)d_in[2];
    const float* wmlp = (const float*)d_in[3];
    float* outp = (float*)d_out;

    short* wsq = (short*)d_ws;                      // 24576 B
    short* wsm = wsq + WSQ_SHORTS;                  // 73728 B  (total 98304 B)

    prep_pack<<<128, 256, 0, stream>>>(wqkv, wmlp, wsq, wsm);

    dim3 grid(WW/TW, HH/TH, 4);
    fused_mfma<<<grid, 256, 0, stream>>>(x, wsq, bqkv, wsm, outp);
}

// Round 10
// 236.483 us; speedup vs baseline: 1.0646x; 1.0646x over previous
//
#include <hip/hip_runtime.h>
#include <hip/hip_bf16.h>

typedef __attribute__((ext_vector_type(8))) short short8;
typedef __attribute__((ext_vector_type(4))) short short4_;
typedef __attribute__((ext_vector_type(4))) float float4_;
typedef __attribute__((ext_vector_type(4))) unsigned int uint4_;

#define CH 64
#define HH 256
#define WW 256
#define HW (HH*WW)
#define CHW (CH*HW)

#define TW 16
#define TH 8
#define XPW 20
#define XPH 12
#define NXP 240        // x/qkv halo set (halo 2)
#define OPW 18
#define OPH 10
#define NOP 180        // out1 set (halo 1)

#define XLS 72         // x staging stride (144 B; R6 showed 64 collapses banks)
#define KQ2 40         // k/q stride (80 B): bank starts step 20%32 -> spread
#define VS  32         // vbuf stride + granule swizzle (R5-R8)
#define O1S 64         // o1b stride + granule swizzle ^pix&7 (R5-R8)
#define TBS 132        // tb2 row stride (floats): [64ch][132]

// LDS regions (shorts), SMEM 19200 = 38400 B -> 4 blocks/CU:
//  xls   [0, 17280)
//  QK:   kbuf2 [0, 9600) = [240][40] ; qbuf2 [9600, 16800) = [180][40]
//  V:    vbuf  [0, 7680) = [240][32]sw ; o1b [7680, 19200) = [180][64]sw
//  epi:  tb2   [0, 16896)  floats [64][132]
#define QB2_OFF 9600
#define O1_OFF  7680
#define SMEM_SHORTS 19200
// Occupancy is VGPR-capped at 4 waves/SIMD (VGPR=84, halving steps at 64/128,
// round-6 evidence). Round-9 evidence: merging phases to cut barriers while
// ADDING per-thread work regresses (VALU 30->34%, time +13%). This round =
// round-8 structure (best: 148 us) + flipped all-b128 epilogue only.

// ws layout: wsq bf16 [0,24576) ; wsm bf16 [24576, 98304)
#define WSQ_SHORTS 12288
#define WSM_SHORTS 36864

__device__ __forceinline__ float blo(unsigned u) {      // even channel of pair
    return __uint_as_float(u << 16);
}
__device__ __forceinline__ float bhi(unsigned u) {      // odd channel of pair
    return __uint_as_float(u & 0xffff0000u);
}
__device__ __forceinline__ short f2bs(float f) {
    __hip_bfloat16 h = __float2bfloat16(f);
    short s; __builtin_memcpy(&s, &h, 2); return s;
}
__device__ __forceinline__ unsigned pack2(float a, float b) {
    return (unsigned)(unsigned short)f2bs(a) |
           ((unsigned)(unsigned short)f2bs(b) << 16);
}

// xls swizzled index: channel c of halo pixel pix
__device__ __forceinline__ int xls_idx(int pix, int c) {
    int g = ((c >> 3) ^ ((pix >> 2) & 7));
    return pix * XLS + g * 8 + (c & 7);
}
// o1b swizzled index (granule = 16B block of 8 channels)
__device__ __forceinline__ int o1_idx(int pix, int c) {
    int g = (((c >> 3) ^ pix) & 7);
    return pix * O1S + g * 8 + (c & 7);
}
// vbuf swizzle key for pixel p
__device__ __forceinline__ int vswz(int p) {
    return (p ^ (p >> 2)) & 3;
}

#if defined(__has_builtin)
#if __has_builtin(__builtin_amdgcn_fdot2_f32_bf16)
#define HAS_BF16_DOT2 1
#endif
#endif
#ifdef HAS_BF16_DOT2
typedef __bf16 bf16x2 __attribute__((ext_vector_type(2)));
__device__ __forceinline__ float dot2acc(unsigned a, unsigned b, float acc) {
    return __builtin_amdgcn_fdot2_f32_bf16(__builtin_bit_cast(bf16x2, a),
                                           __builtin_bit_cast(bf16x2, b),
                                           acc, false);
}
#else
__device__ __forceinline__ float dot2acc(unsigned a, unsigned b, float acc) {
    acc += blo(a) * blo(b);
    acc += bhi(a) * bhi(b);
    return acc;
}
#endif

// ---- prep: pack wqkv/wmlp to bf16 in exact fragment order -------------------
// For mfma_f32_16x16x32_bf16, A and B fragments are symmetric (lane&15 is the
// non-K index), so this pack order serves wsq as the A operand of the
// swapped-operand gemms (round-8 verified).
__global__ void prep_pack(const float* __restrict__ wqkv,
                          const float* __restrict__ wmlp,
                          short* __restrict__ wsq, short* __restrict__ wsm) {
    int idx = blockIdx.x * blockDim.x + threadIdx.x;
    int stride = gridDim.x * blockDim.x;
    for (int e = idx; e < WSQ_SHORTS; e += stride) {
        int j = e & 7, lane = (e >> 3) & 63;
        int ks = (e >> 9) & 1, q16 = (e >> 10) & 3, sec = e >> 12;
        int row = sec*64 + q16*16 + (lane & 15);
        int kk  = ks*32 + (lane >> 4)*8 + j;
        wsq[e] = f2bs(wqkv[(size_t)row*64 + kk]);
    }
    for (int e = idx; e < WSM_SHORTS; e += stride) {
        int j = e & 7, lane = (e >> 3) & 63;
        int rest = e >> 9;            // 0..71
        int nt = rest / 18, ks = rest % 18;
        int o   = nt*16 + (lane & 15);
        int cin = (ks & 1)*32 + (lane >> 4)*8 + j;
        int tap = ks >> 1;
        wsm[e] = f2bs(wmlp[(size_t)o*576 + cin*9 + tap]);
    }
}

// ---- fused kernel -----------------------------------------------------------
// __launch_bounds__(256,3): (256,4) pinned the allocator at the 64-VGPR step
// and spilled (+250 MB HBM, round-1 evidence).
// Swapped MFMA operands (round-8 verified, 168->148): mfma(w, x, c) gives
// D[outch][pixel] -> one ds_write_b64 of 4 consecutive channels per tile.
__global__ __launch_bounds__(256, 3) void fused_mfma(
    const float* __restrict__ x, const short* __restrict__ wsq,
    const float* __restrict__ bqkv, const short* __restrict__ wsm,
    float* __restrict__ out)
{
    __shared__ __align__(16) short smem[SMEM_SHORTS];
    short* xls   = smem;                             // phase X only (swizzled)
    short* kbuf2 = smem;                             // [240][40] QK rounds
    short* qbuf2 = smem + QB2_OFF;                   // [180][40] QK rounds
    short* vbuf  = smem;                             // [240][32]sw V rounds
    short* o1b   = smem + O1_OFF;                    // [180][64]sw V/conv
    float* tb2   = (float*)smem;                     // [64][132] epilogue

    const int t    = threadIdx.x;
    const int w    = t >> 6;
    const int lane = t & 63;
    const int n16  = lane & 15;
    const int quad = lane >> 4;

    // XCD-chunk swizzle (round-2 verified: FETCH 260->58 MB): XCD k owns a
    // contiguous chunk of tiles. 2048 % 8 == 0 -> bijective.
    const int d   = blockIdx.x + (blockIdx.y << 4) + (blockIdx.z << 9);
    const int nn  = ((d & 7) << 8) | (d >> 3);
    const int b   = nn >> 9;
    const int rem = nn & 511;
    const int gy0 = (rem >> 4) * TH;
    const int gx0 = (rem & 15) * TW;
    const float* xb = x + (size_t)b * CHW;

    // ---- phase X: stage x halo into LDS bf16. Channel-PAIR packed b32
    // writes + granule swizzle (round-4 verified: conflicts 1.87e7 -> 6.7e6).
    for (int slot = t; slot < 32*12*6; slot += 256) {
        int s6 = slot % 6, y = (slot / 6) % 12, c2 = slot / 72;
        int c  = c2 * 2;
        int gy = gy0 - 2 + y;
        int gxb = gx0 - 4 + s6*4;
        float v0[4], v1[4];
        bool gyok = (unsigned)gy < HH;
        if (gyok && gxb >= 0 && gxb + 3 < WW) {
            float4_ f0 = *(const float4_*)(xb + (size_t)c*HW + gy*WW + gxb);
            float4_ f1 = *(const float4_*)(xb + (size_t)(c+1)*HW + gy*WW + gxb);
            #pragma unroll
            for (int i = 0; i < 4; ++i) { v0[i] = f0[i]; v1[i] = f1[i]; }
        } else {
            #pragma unroll
            for (int i = 0; i < 4; ++i) {
                int gx = gxb + i;
                bool ok = gyok && (unsigned)gx < WW;
                v0[i] = ok ? xb[(size_t)c*HW + gy*WW + gx] : 0.f;
                v1[i] = ok ? xb[(size_t)(c+1)*HW + gy*WW + gx] : 0.f;
            }
        }
        #pragma unroll
        for (int i = 0; i < 4; ++i) {
            int pxc = s6*4 + i - 2;
            if ((unsigned)pxc < XPW)
                *(unsigned*)&xls[xls_idx(y*XPW + pxc, c)] = pack2(v0[i], v1[i]);
        }
    }
    __syncthreads();

    // per-tile OOB mask: bit i -> pixel (w*4+i)*16 + n16 (uniform in quad/r
    // under the swapped-operand C layout)
    unsigned okb = 0;
    #pragma unroll
    for (int i = 0; i < 4; ++i) {
        int p = (w*4 + i)*16 + n16;
        if (p < NXP) {
            int gy = gy0 - 2 + p / XPW, gx = gx0 - 2 + p % XPW;
            if (((unsigned)gy < HH) && ((unsigned)gx < WW))
                okb |= 1u << i;
        }
    }

    // ---- A-frags (swizzled reads, static-indexed) + residual capture
    short8 afr[4][2];
    #pragma unroll
    for (int i = 0; i < 4; ++i) {
        int p = (w*4 + i)*16 + n16;
        int pr = (p < NXP) ? p : 0;        // clamped dummy for wave3/i3
        #pragma unroll
        for (int ks = 0; ks < 2; ++ks)
            afr[i][ks] = *(const short8*)&xls[xls_idx(pr, ks*32 + quad*8)];
    }
    // per-thread attention pixel
    const int op_py = t / OPW, op_px = t % OPW;
    const int ogy = gy0 - 1 + op_py, ogx = gx0 - 1 + op_px;
    const bool oin = (t < NOP) && ((unsigned)ogy < HH) && ((unsigned)ogx < WW);
    const int xpix = (op_py + 1)*XPW + (op_px + 1);
    short8 resi[8];
    if (t < NOP) {
        #pragma unroll
        for (int g = 0; g < 8; ++g)
            resi[g] = *(const short8*)&xls[xls_idx(xpix, g*8)];
    }
    __syncthreads();   // xls dead; k/q regions may now be written

    // B-fragment loader (global, L2-resident 24 KB)
    auto wload = [&](int sec, int q16, int ks) -> short8 {
        return *(const short8*)&wsq[(((sec*4 + q16)*2 + ks) << 9) + lane*8];
    };
    // 4 biases for channels base+quad*4+{0..3}
    auto bload = [&](int base) -> float4_ {
        return *(const float4_*)&bqkv[base + quad*4];
    };
    // gemm 16 out-ch, swapped operands: D[ch=quad*4+r][pix=n16]; one b64
    // store of 4 consecutive channels per tile
    auto gemm_k = [&](short8 w0, short8 w1, float4_ b4, int coff) {
        #pragma unroll
        for (int i = 0; i < 4; ++i) {
            int p = (w*4 + i)*16 + n16;
            float4_ c = {0.f, 0.f, 0.f, 0.f};
            c = __builtin_amdgcn_mfma_f32_16x16x32_bf16(w0, afr[i][0], c, 0, 0, 0);
            c = __builtin_amdgcn_mfma_f32_16x16x32_bf16(w1, afr[i][1], c, 0, 0, 0);
            if (p < NXP) {
                bool ok = (okb >> i) & 1u;
                short4_ s;
                #pragma unroll
                for (int r = 0; r < 4; ++r) s[r] = ok ? f2bs(c[r] + b4[r]) : (short)0;
                *(short4_*)&kbuf2[p*KQ2 + coff + quad*4] = s;
            }
        }
    };
    auto gemm_v = [&](short8 w0, short8 w1, float4_ b4, int coff) {
        #pragma unroll
        for (int i = 0; i < 4; ++i) {
            int p = (w*4 + i)*16 + n16;
            float4_ c = {0.f, 0.f, 0.f, 0.f};
            c = __builtin_amdgcn_mfma_f32_16x16x32_bf16(w0, afr[i][0], c, 0, 0, 0);
            c = __builtin_amdgcn_mfma_f32_16x16x32_bf16(w1, afr[i][1], c, 0, 0, 0);
            if (p < NXP) {
                bool ok = (okb >> i) & 1u;
                short4_ s;
                #pragma unroll
                for (int r = 0; r < 4; ++r) s[r] = ok ? f2bs(c[r] + b4[r]) : (short)0;
                int cc = coff + quad*4;
                int idx = p*VS + ((((cc >> 3) ^ vswz(p)) & 3) << 3) + (cc & 7);
                *(short4_*)&vbuf[idx] = s;
            }
        }
    };
    auto gemm_q = [&](short8 w0, short8 w1, float4_ b4, int coff) {
        #pragma unroll
        for (int i = 0; i < 4; ++i) {
            int p = (w*4 + i)*16 + n16;
            float4_ c = {0.f, 0.f, 0.f, 0.f};
            c = __builtin_amdgcn_mfma_f32_16x16x32_bf16(w0, afr[i][0], c, 0, 0, 0);
            c = __builtin_amdgcn_mfma_f32_16x16x32_bf16(w1, afr[i][1], c, 0, 0, 0);
            int py = p / XPW, px = p % XPW;
            if ((unsigned)(py - 1) < (unsigned)OPH &&
                (unsigned)(px - 1) < (unsigned)OPW) {
                int op = (py - 1)*OPW + (px - 1);
                short4_ s;
                #pragma unroll
                for (int r = 0; r < 4; ++r) s[r] = f2bs(c[r] + b4[r]);
                *(short4_*)&qbuf2[op*KQ2 + coff + quad*4] = s;
            }
        }
    };

    // ---- QK: 2 rounds x 32 channels
    float dots[9];
    #pragma unroll
    for (int n2 = 0; n2 < 9; ++n2) dots[n2] = 0.f;

    short8 pw0 = wload(0,0,0), pw1 = wload(0,0,1);   // prefetched first pair

    #pragma unroll
    for (int rr = 0; rr < 2; ++rr) {
        {
            short8 b0 = wload(0, 2*rr+1, 0), b1 = wload(0, 2*rr+1, 1);
            gemm_q(pw0, pw1, bload((2*rr)*16), 0);
            gemm_q(b0,  b1,  bload((2*rr+1)*16), 16);
            short8 c0 = wload(1, 2*rr,   0), c1 = wload(1, 2*rr,   1);
            short8 d0 = wload(1, 2*rr+1, 0), d1 = wload(1, 2*rr+1, 1);
            gemm_k(c0, c1, bload(64 + (2*rr)*16),  0);
            gemm_k(d0, d1, bload(64 + (2*rr+1)*16), 16);
        }
        __syncthreads();
        // prefetch next phase's first pair AFTER the barrier (drains at the
        // NEXT barrier; compiler emits vmcnt(0) at every s_barrier)
        if (rr == 0) { pw0 = wload(0, 2, 0); pw1 = wload(0, 2, 1); }
        else         { pw0 = wload(2, 0, 0); pw1 = wload(2, 0, 1); }
        if (oin) {
            uint4_ qa = *(const uint4_*)&qbuf2[t*KQ2];
            uint4_ qb = *(const uint4_*)&qbuf2[t*KQ2 + 8];
            uint4_ qc = *(const uint4_*)&qbuf2[t*KQ2 + 16];
            uint4_ qd = *(const uint4_*)&qbuf2[t*KQ2 + 24];
            #pragma unroll
            for (int n2 = 0; n2 < 9; ++n2) {
                int np = xpix + (n2/3 - 1)*XPW + (n2%3 - 1);
                uint4_ ka = *(const uint4_*)&kbuf2[np*KQ2];
                uint4_ kb = *(const uint4_*)&kbuf2[np*KQ2 + 8];
                uint4_ kc = *(const uint4_*)&kbuf2[np*KQ2 + 16];
                uint4_ kd = *(const uint4_*)&kbuf2[np*KQ2 + 24];
                // 4 independent 4-deep chains (round-8)
                float sA = dots[n2], sB = 0.f, sC = 0.f, sD = 0.f;
                #pragma unroll
                for (int j = 0; j < 4; ++j) sA = dot2acc(qa[j], ka[j], sA);
                #pragma unroll
                for (int j = 0; j < 4; ++j) sB = dot2acc(qb[j], kb[j], sB);
                #pragma unroll
                for (int j = 0; j < 4; ++j) sC = dot2acc(qc[j], kc[j], sC);
                #pragma unroll
                for (int j = 0; j < 4; ++j) sD = dot2acc(qd[j], kd[j], sD);
                dots[n2] = (sA + sB) + (sC + sD);
            }
        }
        __syncthreads();
    }

    // ---- softmax (registers)
    float attn[9];
    if (oin) {
        float mx = -1e30f;
        #pragma unroll
        for (int n2 = 0; n2 < 9; ++n2) { dots[n2] *= 0.125f; mx = fmaxf(mx, dots[n2]); }
        float se = 0.f;
        #pragma unroll
        for (int n2 = 0; n2 < 9; ++n2) { attn[n2] = __expf(dots[n2] - mx); se += attn[n2]; }
        float inv = 1.f / se;
        #pragma unroll
        for (int n2 = 0; n2 < 9; ++n2) attn[n2] *= inv;
    }

    // ---- V: 2 rounds x 32 channels
    #pragma unroll
    for (int rr2 = 0; rr2 < 2; ++rr2) {
        {
            short8 b2 = wload(2, 2*rr2+1, 0), b3 = wload(2, 2*rr2+1, 1);
            gemm_v(pw0, pw1, bload(128 + (2*rr2)*16), 0);
            gemm_v(b2,  b3,  bload(128 + (2*rr2+1)*16), 16);
        }
        __syncthreads();
        if (rr2 == 0) { pw0 = wload(2, 2, 0); pw1 = wload(2, 2, 1); }
        if (t < NOP) {
            #pragma unroll
            for (int h2 = 0; h2 < 2; ++h2) {
                const int kg = rr2*2 + h2;           // 16-ch group 0..3
                short8 s0, s1;
                if (oin) {
                    float o1[16];
                    uint4_ r0 = __builtin_bit_cast(uint4_, resi[kg*2]);
                    uint4_ r1 = __builtin_bit_cast(uint4_, resi[kg*2 + 1]);
                    #pragma unroll
                    for (int j = 0; j < 4; ++j) {
                        o1[2*j]     = blo(r0[j]); o1[2*j + 1]     = bhi(r0[j]);
                        o1[8 + 2*j] = blo(r1[j]); o1[8 + 2*j + 1] = bhi(r1[j]);
                    }
                    #pragma unroll
                    for (int n2 = 0; n2 < 9; ++n2) {
                        float a = attn[n2];
                        int np = xpix + (n2/3 - 1)*XPW + (n2%3 - 1);
                        int sw = vswz(np);
                        uint4_ va = *(const uint4_*)&vbuf[np*VS + (((h2*2)   ^ sw) << 3)];
                        uint4_ vb = *(const uint4_*)&vbuf[np*VS + (((h2*2+1) ^ sw) << 3)];
                        #pragma unroll
                        for (int j = 0; j < 4; ++j) {
                            o1[2*j]         += a * blo(va[j]);
                            o1[2*j + 1]     += a * bhi(va[j]);
                            o1[8 + 2*j]     += a * blo(vb[j]);
                            o1[8 + 2*j + 1] += a * bhi(vb[j]);
                        }
                    }
                    #pragma unroll
                    for (int j = 0; j < 8; ++j) {
                        s0[j] = f2bs(o1[j]);
                        s1[j] = f2bs(o1[8 + j]);
                    }
                } else {
                    #pragma unroll
                    for (int j = 0; j < 8; ++j) { s0[j] = 0; s1[j] = 0; }  // conv zero-pad
                }
                *(short8*)&o1b[o1_idx(t, kg*16)]     = s0;
                *(short8*)&o1b[o1_idx(t, kg*16 + 8)] = s1;
            }
        }
        __syncthreads();
    }

    // ---- 3x3 conv 64->64 as one MFMA burst (K=576 tap-major), B from ws.
    // Weights loaded IN-LOOP (round-5 cw/nw rotation spilled; reverted).
    float4_ acc[4][2];
    #pragma unroll
    for (int nt = 0; nt < 4; ++nt) {
        acc[nt][0] = (float4_){0.f,0.f,0.f,0.f};
        acc[nt][1] = (float4_){0.f,0.f,0.f,0.f};
    }
    const int mtc0 = w*2, mtc1 = w*2 + 1;
    for (int ks = 0; ks < 18; ++ks) {
        int tap = ks >> 1;
        int dy = tap/3 - 1, dx = tap%3 - 1;
        int cin0 = (ks & 1)*32 + quad*8;
        int pixA = (mtc0 + 1 + dy)*OPW + (n16 + 1 + dx);
        int pixB = (mtc1 + 1 + dy)*OPW + (n16 + 1 + dx);
        short8 a0 = *(const short8*)&o1b[o1_idx(pixA, cin0)];
        short8 a1 = *(const short8*)&o1b[o1_idx(pixB, cin0)];
        #pragma unroll
        for (int nt = 0; nt < 4; ++nt) {
            short8 bb = *(const short8*)&wsm[((nt*18 + ks) << 9) + lane*8];
            acc[nt][0] = __builtin_amdgcn_mfma_f32_16x16x32_bf16(a0, bb, acc[nt][0], 0, 0, 0);
            acc[nt][1] = __builtin_amdgcn_mfma_f32_16x16x32_bf16(a1, bb, acc[nt][1], 0, 0, 0);
        }
    }
    __syncthreads();   // tb2 overlaps vbuf/o1b: all conv reads must land

    // ---- epilogue (round-9 graft): single flipped tbuf [ch][132], all-b128.
    // Write: D[ch=nt*16+n16][pix]: pixel y=w*2+h, x=quad*4+{0..3} -> float4
    // over x. Banks: start 4*((n16+quad)%8)+... covers all 32, 8/bank = b128
    // minimum. Replaces 32 scalar LDS writes + 32 reads + 32 scalar global
    // stores + 2 barriers with 8 b128 writes + 8 reads + 8 dwordx4 stores +
    // 1 barrier.
    #pragma unroll
    for (int nt = 0; nt < 4; ++nt)
        #pragma unroll
        for (int h = 0; h < 2; ++h) {
            float4_ rv;
            #pragma unroll
            for (int r = 0; r < 4; ++r) rv[r] = fmaxf(acc[nt][h][r], 0.f);
            *(float4_*)&tb2[(nt*16 + n16)*TBS + (w*2 + h)*16 + quad*4] = rv;
        }
    __syncthreads();
    #pragma unroll
    for (int k = 0; k < 8; ++k) {
        int unit = t + k*256;                  // 2048 units: ch(64) y(8) xg(4)
        int ch = unit >> 5, y = (unit >> 2) & 7, xg = unit & 3;
        float4_ v = *(const float4_*)&tb2[ch*TBS + y*16 + xg*4];
        *(float4_*)(out + (size_t)b*CHW + (size_t)ch*HW
                    + (size_t)(gy0 + y)*WW + (gx0 + xg*4)) = v;
    }
}

extern "C" void kernel_launch(void* const* d_in, const int* in_sizes, int n_in,
                              void* d_out, int out_size, void* d_ws, size_t ws_size,
                              hipStream_t stream) {
    const float* x    = (const float*)d_in[0];
    const float* wqkv = (const float*)d_in[1];
    const float* bqkv = (const float*)d_in[2];
    const float* wmlp = (const float*)d_in[3];
    float* outp = (float*)d_out;

    short* wsq = (short*)d_ws;                      // 24576 B
    short* wsm = wsq + WSQ_SHORTS;                  // 73728 B  (total 98304 B)

    prep_pack<<<128, 256, 0, stream>>>(wqkv, wmlp, wsq, wsm);

    dim3 grid(WW/TW, HH/TH, 4);
    fused_mfma<<<grid, 256, 0, stream>>>(x, wsq, bqkv, wsm, outp);
}

// Round 11
// 231.331 us; speedup vs baseline: 1.0883x; 1.0223x over previous
//
#include <hip/hip_runtime.h>
#include <hip/hip_bf16.h>

typedef __attribute__((ext_vector_type(8))) short short8;
typedef __attribute__((ext_vector_type(4))) short short4_;
typedef __attribute__((ext_vector_type(4))) float float4_;
typedef __attribute__((ext_vector_type(4))) unsigned int uint4_;

#define CH 64
#define HH 256
#define WW 256
#define HW (HH*WW)
#define CHW (CH*HW)

#define TW 16
#define TH 8
#define XPW 20
#define XPH 12
#define NXP 240        // x/qkv halo set (halo 2)
#define OPW 18
#define OPH 10
#define NOP 180        // out1 set (halo 1)

#define XLS 72         // x staging stride (144 B; R6 showed 64 collapses banks)
#define KQ2 40         // k/q stride (80 B): bank starts step 20%32 -> spread
#define VS  32         // vbuf stride + granule swizzle (R5-R8)
#define O1S 64         // o1b stride + granule swizzle ^pix&7 (R5-R8)
#define TBS 132        // tb2 row stride (floats): [64ch][132]

// LDS regions (shorts), SMEM 19200 = 38400 B -> 4 blocks/CU (the binding
// occupancy cap: 5 blocks would need 192000 B > 160 KiB).
//  xls   [0, 17280)
//  QK:   kbuf2 [0, 9600) = [240][40] ; qbuf2 [9600, 16800) = [180][40]
//  V:    vbuf  [0, 7680) = [240][32]sw ; o1b [7680, 19200) = [180][64]sw
//  epi:  tb2   [0, 16896)  floats [64][132]
#define QB2_OFF 9600
#define O1_OFF  7680
#define SMEM_SHORTS 19200
// VGPR budget note (corrected from R6's misdiagnosis): 4 blocks/CU = 4
// waves/SIMD needs VGPR <= 128, we sit at 84 -> 44 regs of FREE headroom.
// That headroom funds the conv-loop unroll-2 software pipeline this round.
// (256,4) launch bounds remains poison: allocator pins to the 64-reg step
// and spills (round-1 evidence).

// ws layout: wsq bf16 [0,24576) ; wsm bf16 [24576, 98304)
#define WSQ_SHORTS 12288
#define WSM_SHORTS 36864

__device__ __forceinline__ float blo(unsigned u) {      // even channel of pair
    return __uint_as_float(u << 16);
}
__device__ __forceinline__ float bhi(unsigned u) {      // odd channel of pair
    return __uint_as_float(u & 0xffff0000u);
}
__device__ __forceinline__ short f2bs(float f) {
    __hip_bfloat16 h = __float2bfloat16(f);
    short s; __builtin_memcpy(&s, &h, 2); return s;
}
__device__ __forceinline__ unsigned pack2(float a, float b) {
    return (unsigned)(unsigned short)f2bs(a) |
           ((unsigned)(unsigned short)f2bs(b) << 16);
}

// xls swizzled index: channel c of halo pixel pix
__device__ __forceinline__ int xls_idx(int pix, int c) {
    int g = ((c >> 3) ^ ((pix >> 2) & 7));
    return pix * XLS + g * 8 + (c & 7);
}
// o1b swizzled index (granule = 16B block of 8 channels)
__device__ __forceinline__ int o1_idx(int pix, int c) {
    int g = (((c >> 3) ^ pix) & 7);
    return pix * O1S + g * 8 + (c & 7);
}
// vbuf swizzle key for pixel p
__device__ __forceinline__ int vswz(int p) {
    return (p ^ (p >> 2)) & 3;
}

#if defined(__has_builtin)
#if __has_builtin(__builtin_amdgcn_fdot2_f32_bf16)
#define HAS_BF16_DOT2 1
#endif
#endif
#ifdef HAS_BF16_DOT2
typedef __bf16 bf16x2 __attribute__((ext_vector_type(2)));
__device__ __forceinline__ float dot2acc(unsigned a, unsigned b, float acc) {
    return __builtin_amdgcn_fdot2_f32_bf16(__builtin_bit_cast(bf16x2, a),
                                           __builtin_bit_cast(bf16x2, b),
                                           acc, false);
}
#else
__device__ __forceinline__ float dot2acc(unsigned a, unsigned b, float acc) {
    acc += blo(a) * blo(b);
    acc += bhi(a) * bhi(b);
    return acc;
}
#endif

// ---- prep: pack wqkv/wmlp to bf16 in exact fragment order -------------------
// For mfma_f32_16x16x32_bf16, A and B fragments are symmetric (lane&15 is the
// non-K index), so this pack order serves wsq as the A operand of the
// swapped-operand gemms (round-8 verified).
// Round-11: the 1/8 QK scale is folded into the q-section weights here
// (power-of-two scale: bf16 mantissa unchanged, bit-exact) and into the
// q bias at load time in the kernel — removes the dots-scaling pass.
__global__ void prep_pack(const float* __restrict__ wqkv,
                          const float* __restrict__ wmlp,
                          short* __restrict__ wsq, short* __restrict__ wsm) {
    int idx = blockIdx.x * blockDim.x + threadIdx.x;
    int stride = gridDim.x * blockDim.x;
    for (int e = idx; e < WSQ_SHORTS; e += stride) {
        int j = e & 7, lane = (e >> 3) & 63;
        int ks = (e >> 9) & 1, q16 = (e >> 10) & 3, sec = e >> 12;
        int row = sec*64 + q16*16 + (lane & 15);
        int kk  = ks*32 + (lane >> 4)*8 + j;
        float v = wqkv[(size_t)row*64 + kk];
        if (sec == 0) v *= 0.125f;         // fold QK scale into q weights
        wsq[e] = f2bs(v);
    }
    for (int e = idx; e < WSM_SHORTS; e += stride) {
        int j = e & 7, lane = (e >> 3) & 63;
        int rest = e >> 9;            // 0..71
        int nt = rest / 18, ks = rest % 18;
        int o   = nt*16 + (lane & 15);
        int cin = (ks & 1)*32 + (lane >> 4)*8 + j;
        int tap = ks >> 1;
        wsm[e] = f2bs(wmlp[(size_t)o*576 + cin*9 + tap]);
    }
}

// ---- fused kernel -----------------------------------------------------------
// Swapped MFMA operands (round-8 verified, 168->148): mfma(w, x, c) gives
// D[outch][pixel] -> one ds_write_b64 of 4 consecutive channels per tile.
// Round-11: s_setprio(1) around MFMA clusters (T5: 4 independent blocks/CU
// are at different phases -> priority lets MFMA waves preempt other blocks'
// VALU/load waves) + unroll-2 on the conv loop (software-pipelines the
// serial {L2 weight load ~200cy -> 8 MFMA ~64cy} chain; funded by the
// 44-VGPR headroom below the 128 cap).
__global__ __launch_bounds__(256, 3) void fused_mfma(
    const float* __restrict__ x, const short* __restrict__ wsq,
    const float* __restrict__ bqkv, const short* __restrict__ wsm,
    float* __restrict__ out)
{
    __shared__ __align__(16) short smem[SMEM_SHORTS];
    short* xls   = smem;                             // phase X only (swizzled)
    short* kbuf2 = smem;                             // [240][40] QK rounds
    short* qbuf2 = smem + QB2_OFF;                   // [180][40] QK rounds
    short* vbuf  = smem;                             // [240][32]sw V rounds
    short* o1b   = smem + O1_OFF;                    // [180][64]sw V/conv
    float* tb2   = (float*)smem;                     // [64][132] epilogue

    const int t    = threadIdx.x;
    const int w    = t >> 6;
    const int lane = t & 63;
    const int n16  = lane & 15;
    const int quad = lane >> 4;

    // XCD-chunk swizzle (round-2 verified: FETCH 260->58 MB): XCD k owns a
    // contiguous chunk of tiles. 2048 % 8 == 0 -> bijective.
    const int d   = blockIdx.x + (blockIdx.y << 4) + (blockIdx.z << 9);
    const int nn  = ((d & 7) << 8) | (d >> 3);
    const int b   = nn >> 9;
    const int rem = nn & 511;
    const int gy0 = (rem >> 4) * TH;
    const int gx0 = (rem & 15) * TW;
    const float* xb = x + (size_t)b * CHW;

    // ---- phase X: stage x halo into LDS bf16. Channel-PAIR packed b32
    // writes + granule swizzle (round-4 verified: conflicts 1.87e7 -> 6.7e6).
    for (int slot = t; slot < 32*12*6; slot += 256) {
        int s6 = slot % 6, y = (slot / 6) % 12, c2 = slot / 72;
        int c  = c2 * 2;
        int gy = gy0 - 2 + y;
        int gxb = gx0 - 4 + s6*4;
        float v0[4], v1[4];
        bool gyok = (unsigned)gy < HH;
        if (gyok && gxb >= 0 && gxb + 3 < WW) {
            float4_ f0 = *(const float4_*)(xb + (size_t)c*HW + gy*WW + gxb);
            float4_ f1 = *(const float4_*)(xb + (size_t)(c+1)*HW + gy*WW + gxb);
            #pragma unroll
            for (int i = 0; i < 4; ++i) { v0[i] = f0[i]; v1[i] = f1[i]; }
        } else {
            #pragma unroll
            for (int i = 0; i < 4; ++i) {
                int gx = gxb + i;
                bool ok = gyok && (unsigned)gx < WW;
                v0[i] = ok ? xb[(size_t)c*HW + gy*WW + gx] : 0.f;
                v1[i] = ok ? xb[(size_t)(c+1)*HW + gy*WW + gx] : 0.f;
            }
        }
        #pragma unroll
        for (int i = 0; i < 4; ++i) {
            int pxc = s6*4 + i - 2;
            if ((unsigned)pxc < XPW)
                *(unsigned*)&xls[xls_idx(y*XPW + pxc, c)] = pack2(v0[i], v1[i]);
        }
    }
    __syncthreads();

    // per-tile OOB mask: bit i -> pixel (w*4+i)*16 + n16 (uniform in quad/r
    // under the swapped-operand C layout)
    unsigned okb = 0;
    #pragma unroll
    for (int i = 0; i < 4; ++i) {
        int p = (w*4 + i)*16 + n16;
        if (p < NXP) {
            int gy = gy0 - 2 + p / XPW, gx = gx0 - 2 + p % XPW;
            if (((unsigned)gy < HH) && ((unsigned)gx < WW))
                okb |= 1u << i;
        }
    }

    // ---- A-frags (swizzled reads, static-indexed) + residual capture
    short8 afr[4][2];
    #pragma unroll
    for (int i = 0; i < 4; ++i) {
        int p = (w*4 + i)*16 + n16;
        int pr = (p < NXP) ? p : 0;        // clamped dummy for wave3/i3
        #pragma unroll
        for (int ks = 0; ks < 2; ++ks)
            afr[i][ks] = *(const short8*)&xls[xls_idx(pr, ks*32 + quad*8)];
    }
    // per-thread attention pixel
    const int op_py = t / OPW, op_px = t % OPW;
    const int ogy = gy0 - 1 + op_py, ogx = gx0 - 1 + op_px;
    const bool oin = (t < NOP) && ((unsigned)ogy < HH) && ((unsigned)ogx < WW);
    const int xpix = (op_py + 1)*XPW + (op_px + 1);
    short8 resi[8];
    if (t < NOP) {
        #pragma unroll
        for (int g = 0; g < 8; ++g)
            resi[g] = *(const short8*)&xls[xls_idx(xpix, g*8)];
    }
    __syncthreads();   // xls dead; k/q regions may now be written

    // B-fragment loader (global, L2-resident 24 KB)
    auto wload = [&](int sec, int q16, int ks) -> short8 {
        return *(const short8*)&wsq[(((sec*4 + q16)*2 + ks) << 9) + lane*8];
    };
    // 4 biases for channels base+quad*4+{0..3}
    auto bload = [&](int base) -> float4_ {
        return *(const float4_*)&bqkv[base + quad*4];
    };
    // gemm 16 out-ch, swapped operands: D[ch=quad*4+r][pix=n16]; one b64
    // store of 4 consecutive channels per tile
    auto gemm_k = [&](short8 w0, short8 w1, float4_ b4, int coff) {
        __builtin_amdgcn_s_setprio(1);
        #pragma unroll
        for (int i = 0; i < 4; ++i) {
            int p = (w*4 + i)*16 + n16;
            float4_ c = {0.f, 0.f, 0.f, 0.f};
            c = __builtin_amdgcn_mfma_f32_16x16x32_bf16(w0, afr[i][0], c, 0, 0, 0);
            c = __builtin_amdgcn_mfma_f32_16x16x32_bf16(w1, afr[i][1], c, 0, 0, 0);
            if (p < NXP) {
                bool ok = (okb >> i) & 1u;
                short4_ s;
                #pragma unroll
                for (int r = 0; r < 4; ++r) s[r] = ok ? f2bs(c[r] + b4[r]) : (short)0;
                *(short4_*)&kbuf2[p*KQ2 + coff + quad*4] = s;
            }
        }
        __builtin_amdgcn_s_setprio(0);
    };
    auto gemm_v = [&](short8 w0, short8 w1, float4_ b4, int coff) {
        __builtin_amdgcn_s_setprio(1);
        #pragma unroll
        for (int i = 0; i < 4; ++i) {
            int p = (w*4 + i)*16 + n16;
            float4_ c = {0.f, 0.f, 0.f, 0.f};
            c = __builtin_amdgcn_mfma_f32_16x16x32_bf16(w0, afr[i][0], c, 0, 0, 0);
            c = __builtin_amdgcn_mfma_f32_16x16x32_bf16(w1, afr[i][1], c, 0, 0, 0);
            if (p < NXP) {
                bool ok = (okb >> i) & 1u;
                short4_ s;
                #pragma unroll
                for (int r = 0; r < 4; ++r) s[r] = ok ? f2bs(c[r] + b4[r]) : (short)0;
                int cc = coff + quad*4;
                int idx = p*VS + ((((cc >> 3) ^ vswz(p)) & 3) << 3) + (cc & 7);
                *(short4_*)&vbuf[idx] = s;
            }
        }
        __builtin_amdgcn_s_setprio(0);
    };
    auto gemm_q = [&](short8 w0, short8 w1, float4_ b4, int coff) {
        __builtin_amdgcn_s_setprio(1);
        #pragma unroll
        for (int i = 0; i < 4; ++i) {
            int p = (w*4 + i)*16 + n16;
            float4_ c = {0.f, 0.f, 0.f, 0.f};
            c = __builtin_amdgcn_mfma_f32_16x16x32_bf16(w0, afr[i][0], c, 0, 0, 0);
            c = __builtin_amdgcn_mfma_f32_16x16x32_bf16(w1, afr[i][1], c, 0, 0, 0);
            int py = p / XPW, px = p % XPW;
            if ((unsigned)(py - 1) < (unsigned)OPH &&
                (unsigned)(px - 1) < (unsigned)OPW) {
                int op = (py - 1)*OPW + (px - 1);
                short4_ s;
                #pragma unroll
                for (int r = 0; r < 4; ++r) s[r] = f2bs(c[r] + b4[r]);
                *(short4_*)&qbuf2[op*KQ2 + coff + quad*4] = s;
            }
        }
        __builtin_amdgcn_s_setprio(0);
    };

    // ---- QK: 2 rounds x 32 channels
    float dots[9];
    #pragma unroll
    for (int n2 = 0; n2 < 9; ++n2) dots[n2] = 0.f;

    short8 pw0 = wload(0,0,0), pw1 = wload(0,0,1);   // prefetched first pair

    #pragma unroll
    for (int rr = 0; rr < 2; ++rr) {
        {
            short8 b0 = wload(0, 2*rr+1, 0), b1 = wload(0, 2*rr+1, 1);
            // q biases carry the folded 1/8 scale (weights scaled in prep)
            gemm_q(pw0, pw1, bload((2*rr)*16) * 0.125f, 0);
            gemm_q(b0,  b1,  bload((2*rr+1)*16) * 0.125f, 16);
            short8 c0 = wload(1, 2*rr,   0), c1 = wload(1, 2*rr,   1);
            short8 d0 = wload(1, 2*rr+1, 0), d1 = wload(1, 2*rr+1, 1);
            gemm_k(c0, c1, bload(64 + (2*rr)*16),  0);
            gemm_k(d0, d1, bload(64 + (2*rr+1)*16), 16);
        }
        __syncthreads();
        // prefetch next phase's first pair AFTER the barrier (drains at the
        // NEXT barrier; compiler emits vmcnt(0) at every s_barrier)
        if (rr == 0) { pw0 = wload(0, 2, 0); pw1 = wload(0, 2, 1); }
        else         { pw0 = wload(2, 0, 0); pw1 = wload(2, 0, 1); }
        if (oin) {
            uint4_ qa = *(const uint4_*)&qbuf2[t*KQ2];
            uint4_ qb = *(const uint4_*)&qbuf2[t*KQ2 + 8];
            uint4_ qc = *(const uint4_*)&qbuf2[t*KQ2 + 16];
            uint4_ qd = *(const uint4_*)&qbuf2[t*KQ2 + 24];
            #pragma unroll
            for (int n2 = 0; n2 < 9; ++n2) {
                int np = xpix + (n2/3 - 1)*XPW + (n2%3 - 1);
                uint4_ ka = *(const uint4_*)&kbuf2[np*KQ2];
                uint4_ kb = *(const uint4_*)&kbuf2[np*KQ2 + 8];
                uint4_ kc = *(const uint4_*)&kbuf2[np*KQ2 + 16];
                uint4_ kd = *(const uint4_*)&kbuf2[np*KQ2 + 24];
                // 4 independent 4-deep chains (round-8)
                float sA = dots[n2], sB = 0.f, sC = 0.f, sD = 0.f;
                #pragma unroll
                for (int j = 0; j < 4; ++j) sA = dot2acc(qa[j], ka[j], sA);
                #pragma unroll
                for (int j = 0; j < 4; ++j) sB = dot2acc(qb[j], kb[j], sB);
                #pragma unroll
                for (int j = 0; j < 4; ++j) sC = dot2acc(qc[j], kc[j], sC);
                #pragma unroll
                for (int j = 0; j < 4; ++j) sD = dot2acc(qd[j], kd[j], sD);
                dots[n2] = (sA + sB) + (sC + sD);
            }
        }
        __syncthreads();
    }

    // ---- softmax (registers; scale already folded into q)
    float attn[9];
    if (oin) {
        float mx = -1e30f;
        #pragma unroll
        for (int n2 = 0; n2 < 9; ++n2) mx = fmaxf(mx, dots[n2]);
        float se = 0.f;
        #pragma unroll
        for (int n2 = 0; n2 < 9; ++n2) { attn[n2] = __expf(dots[n2] - mx); se += attn[n2]; }
        float inv = 1.f / se;
        #pragma unroll
        for (int n2 = 0; n2 < 9; ++n2) attn[n2] *= inv;
    }

    // ---- V: 2 rounds x 32 channels
    #pragma unroll
    for (int rr2 = 0; rr2 < 2; ++rr2) {
        {
            short8 b2 = wload(2, 2*rr2+1, 0), b3 = wload(2, 2*rr2+1, 1);
            gemm_v(pw0, pw1, bload(128 + (2*rr2)*16), 0);
            gemm_v(b2,  b3,  bload(128 + (2*rr2+1)*16), 16);
        }
        __syncthreads();
        if (rr2 == 0) { pw0 = wload(2, 2, 0); pw1 = wload(2, 2, 1); }
        if (t < NOP) {
            #pragma unroll
            for (int h2 = 0; h2 < 2; ++h2) {
                const int kg = rr2*2 + h2;           // 16-ch group 0..3
                short8 s0, s1;
                if (oin) {
                    float o1[16];
                    uint4_ r0 = __builtin_bit_cast(uint4_, resi[kg*2]);
                    uint4_ r1 = __builtin_bit_cast(uint4_, resi[kg*2 + 1]);
                    #pragma unroll
                    for (int j = 0; j < 4; ++j) {
                        o1[2*j]     = blo(r0[j]); o1[2*j + 1]     = bhi(r0[j]);
                        o1[8 + 2*j] = blo(r1[j]); o1[8 + 2*j + 1] = bhi(r1[j]);
                    }
                    #pragma unroll
                    for (int n2 = 0; n2 < 9; ++n2) {
                        float a = attn[n2];
                        int np = xpix + (n2/3 - 1)*XPW + (n2%3 - 1);
                        int sw = vswz(np);
                        uint4_ va = *(const uint4_*)&vbuf[np*VS + (((h2*2)   ^ sw) << 3)];
                        uint4_ vb = *(const uint4_*)&vbuf[np*VS + (((h2*2+1) ^ sw) << 3)];
                        #pragma unroll
                        for (int j = 0; j < 4; ++j) {
                            o1[2*j]         += a * blo(va[j]);
                            o1[2*j + 1]     += a * bhi(va[j]);
                            o1[8 + 2*j]     += a * blo(vb[j]);
                            o1[8 + 2*j + 1] += a * bhi(vb[j]);
                        }
                    }
                    #pragma unroll
                    for (int j = 0; j < 8; ++j) {
                        s0[j] = f2bs(o1[j]);
                        s1[j] = f2bs(o1[8 + j]);
                    }
                } else {
                    #pragma unroll
                    for (int j = 0; j < 8; ++j) { s0[j] = 0; s1[j] = 0; }  // conv zero-pad
                }
                *(short8*)&o1b[o1_idx(t, kg*16)]     = s0;
                *(short8*)&o1b[o1_idx(t, kg*16 + 8)] = s1;
            }
        }
        __syncthreads();
    }

    // ---- 3x3 conv 64->64 as one MFMA burst (K=576 tap-major), B from ws.
    // unroll-2: lets the compiler software-pipeline iteration k+1's weight
    // loads (L2, ~200 cy) under iteration k's 8 MFMA (~64 cy). Transient
    // register cost fits the 44-VGPR headroom (cap 128 for 4 waves/SIMD);
    // watch VGPR_Count — if >128 this spilled and must be reverted.
    float4_ acc[4][2];
    #pragma unroll
    for (int nt = 0; nt < 4; ++nt) {
        acc[nt][0] = (float4_){0.f,0.f,0.f,0.f};
        acc[nt][1] = (float4_){0.f,0.f,0.f,0.f};
    }
    const int mtc0 = w*2, mtc1 = w*2 + 1;
    __builtin_amdgcn_s_setprio(1);
    #pragma unroll 2
    for (int ks = 0; ks < 18; ++ks) {
        int tap = ks >> 1;
        int dy = tap/3 - 1, dx = tap%3 - 1;
        int cin0 = (ks & 1)*32 + quad*8;
        int pixA = (mtc0 + 1 + dy)*OPW + (n16 + 1 + dx);
        int pixB = (mtc1 + 1 + dy)*OPW + (n16 + 1 + dx);
        short8 a0 = *(const short8*)&o1b[o1_idx(pixA, cin0)];
        short8 a1 = *(const short8*)&o1b[o1_idx(pixB, cin0)];
        #pragma unroll
        for (int nt = 0; nt < 4; ++nt) {
            short8 bb = *(const short8*)&wsm[((nt*18 + ks) << 9) + lane*8];
            acc[nt][0] = __builtin_amdgcn_mfma_f32_16x16x32_bf16(a0, bb, acc[nt][0], 0, 0, 0);
            acc[nt][1] = __builtin_amdgcn_mfma_f32_16x16x32_bf16(a1, bb, acc[nt][1], 0, 0, 0);
        }
    }
    __builtin_amdgcn_s_setprio(0);
    __syncthreads();   // tb2 overlaps vbuf/o1b: all conv reads must land

    // ---- epilogue: single flipped tbuf [ch][132], all-b128 (round-10)
    #pragma unroll
    for (int nt = 0; nt < 4; ++nt)
        #pragma unroll
        for (int h = 0; h < 2; ++h) {
            float4_ rv;
            #pragma unroll
            for (int r = 0; r < 4; ++r) rv[r] = fmaxf(acc[nt][h][r], 0.f);
            *(float4_*)&tb2[(nt*16 + n16)*TBS + (w*2 + h)*16 + quad*4] = rv;
        }
    __syncthreads();
    #pragma unroll
    for (int k = 0; k < 8; ++k) {
        int unit = t + k*256;                  // 2048 units: ch(64) y(8) xg(4)
        int ch = unit >> 5, y = (unit >> 2) & 7, xg = unit & 3;
        float4_ v = *(const float4_*)&tb2[ch*TBS + y*16 + xg*4];
        *(float4_*)(out + (size_t)b*CHW + (size_t)ch*HW
                    + (size_t)(gy0 + y)*WW + (gx0 + xg*4)) = v;
    }
}

extern "C" void kernel_launch(void* const* d_in, const int* in_sizes, int n_in,
                              void* d_out, int out_size, void* d_ws, size_t ws_size,
                              hipStream_t stream) {
    const float* x    = (const float*)d_in[0];
    const float* wqkv = (const float*)d_in[1];
    const float* bqkv = (const float*)d_in[2];
    const float* wmlp = (const float*)d_in[3];
    float* outp = (float*)d_out;

    short* wsq = (short*)d_ws;                      // 24576 B
    short* wsm = wsq + WSQ_SHORTS;                  // 73728 B  (total 98304 B)

    prep_pack<<<128, 256, 0, stream>>>(wqkv, wmlp, wsq, wsm);

    dim3 grid(WW/TW, HH/TH, 4);
    fused_mfma<<<grid, 256, 0, stream>>>(x, wsq, bqkv, wsm, outp);
}

// Round 12
// 225.550 us; speedup vs baseline: 1.1162x; 1.0256x over previous
//
#include <hip/hip_runtime.h>
#include <hip/hip_bf16.h>

typedef __attribute__((ext_vector_type(8))) short short8;
typedef __attribute__((ext_vector_type(4))) short short4_;
typedef __attribute__((ext_vector_type(4))) float float4_;
typedef __attribute__((ext_vector_type(4))) unsigned int uint4_;

#define CH 64
#define HH 256
#define WW 256
#define HW (HH*WW)
#define CHW (CH*HW)

#define TW 16
#define TH 8
#define XPW 20
#define XPH 12
#define NXP 240        // x/qkv halo set (halo 2)
#define OPW 18
#define OPH 10
#define NOP 180        // out1 set (halo 1)

#define XLS 72         // x staging stride (144 B; R6 showed 64 collapses banks)
#define KQ2 40         // k/q stride (80 B): bank starts step 20%32 -> spread
#define VS  32         // vbuf stride + granule swizzle (R5-R8)
#define O1S 64         // o1b stride + granule swizzle ^pix&7 (R5-R8)
#define TBS 132        // tb2 row stride (floats): [64ch][132]

// LDS regions (shorts), SMEM 19200 = 38400 B -> 4 blocks/CU (the binding
// occupancy cap together with the VGPR<=128 step for 4 waves/SIMD).
//  xls   [0, 17280)
//  QK:   kbuf2 [0, 9600) = [240][40] ; qbuf2 [9600, 16800) = [180][40]
//  V:    vbuf  [0, 7680) = [240][32]sw ; o1b [7680, 19200) = [180][64]sw
//  epi:  tb2   [0, 16896)  floats [64][132]
#define QB2_OFF 9600
#define O1_OFF  7680
#define SMEM_SHORTS 19200
// VGPR budget: 4 waves/SIMD needs <=128; base is 84 -> 44 headroom. Round-12
// spends ~32 of it on the conv weight rotation (R7 falsified the old "R5
// rotation spilled" attribution — R5's VGPR never changed; its regression
// was the concurrent layout change). (256,4) launch bounds remains poison.

// ws layout: wsq bf16 [0,24576) ; wsm bf16 [24576, 98304)
#define WSQ_SHORTS 12288
#define WSM_SHORTS 36864

__device__ __forceinline__ float blo(unsigned u) {      // even channel of pair
    return __uint_as_float(u << 16);
}
__device__ __forceinline__ float bhi(unsigned u) {      // odd channel of pair
    return __uint_as_float(u & 0xffff0000u);
}
__device__ __forceinline__ short f2bs(float f) {
    __hip_bfloat16 h = __float2bfloat16(f);
    short s; __builtin_memcpy(&s, &h, 2); return s;
}
__device__ __forceinline__ unsigned pack2(float a, float b) {
    return (unsigned)(unsigned short)f2bs(a) |
           ((unsigned)(unsigned short)f2bs(b) << 16);
}

// xls swizzled index: channel c of halo pixel pix
__device__ __forceinline__ int xls_idx(int pix, int c) {
    int g = ((c >> 3) ^ ((pix >> 2) & 7));
    return pix * XLS + g * 8 + (c & 7);
}
// o1b swizzled index (granule = 16B block of 8 channels)
__device__ __forceinline__ int o1_idx(int pix, int c) {
    int g = (((c >> 3) ^ pix) & 7);
    return pix * O1S + g * 8 + (c & 7);
}
// vbuf swizzle key for pixel p
__device__ __forceinline__ int vswz(int p) {
    return (p ^ (p >> 2)) & 3;
}

#if defined(__has_builtin)
#if __has_builtin(__builtin_amdgcn_fdot2_f32_bf16)
#define HAS_BF16_DOT2 1
#endif
#endif
#ifdef HAS_BF16_DOT2
typedef __bf16 bf16x2 __attribute__((ext_vector_type(2)));
__device__ __forceinline__ float dot2acc(unsigned a, unsigned b, float acc) {
    return __builtin_amdgcn_fdot2_f32_bf16(__builtin_bit_cast(bf16x2, a),
                                           __builtin_bit_cast(bf16x2, b),
                                           acc, false);
}
#else
__device__ __forceinline__ float dot2acc(unsigned a, unsigned b, float acc) {
    acc += blo(a) * blo(b);
    acc += bhi(a) * bhi(b);
    return acc;
}
#endif

// ---- prep: pack wqkv/wmlp to bf16 in exact fragment order -------------------
// A/B fragments of mfma_f32_16x16x32_bf16 are symmetric, so this pack order
// serves wsq as the A operand of the swapped-operand gemms (round-8).
// The 1/8 QK scale is folded into the q-section weights (power-of-two:
// bit-exact in bf16) and into the q bias at load time (round-11).
__global__ void prep_pack(const float* __restrict__ wqkv,
                          const float* __restrict__ wmlp,
                          short* __restrict__ wsq, short* __restrict__ wsm) {
    int idx = blockIdx.x * blockDim.x + threadIdx.x;
    int stride = gridDim.x * blockDim.x;
    for (int e = idx; e < WSQ_SHORTS; e += stride) {
        int j = e & 7, lane = (e >> 3) & 63;
        int ks = (e >> 9) & 1, q16 = (e >> 10) & 3, sec = e >> 12;
        int row = sec*64 + q16*16 + (lane & 15);
        int kk  = ks*32 + (lane >> 4)*8 + j;
        float v = wqkv[(size_t)row*64 + kk];
        if (sec == 0) v *= 0.125f;         // fold QK scale into q weights
        wsq[e] = f2bs(v);
    }
    for (int e = idx; e < WSM_SHORTS; e += stride) {
        int j = e & 7, lane = (e >> 3) & 63;
        int rest = e >> 9;            // 0..71
        int nt = rest / 18, ks = rest % 18;
        int o   = nt*16 + (lane & 15);
        int cin = (ks & 1)*32 + (lane >> 4)*8 + j;
        int tap = ks >> 1;
        wsm[e] = f2bs(wmlp[(size_t)o*576 + cin*9 + tap]);
    }
}

// ---- fused kernel -----------------------------------------------------------
// Swapped MFMA operands (round-8, 168->148): mfma(w, x, c) gives
// D[outch][pixel] -> one ds_write_b64 per tile. s_setprio(1) around MFMA
// clusters (round-11, T5). Round-12: conv weight software pipeline — ks=0's
// 4 fragments preloaded DURING PV round 1 (their ~200cy L2 latency hides
// under PV's VALU; the barrier's vmcnt(0) drain guarantees arrival), then a
// depth-1 rotation (load ks+1 while ks's 8 MFMAs run).
__global__ __launch_bounds__(256, 3) void fused_mfma(
    const float* __restrict__ x, const short* __restrict__ wsq,
    const float* __restrict__ bqkv, const short* __restrict__ wsm,
    float* __restrict__ out)
{
    __shared__ __align__(16) short smem[SMEM_SHORTS];
    short* xls   = smem;                             // phase X only (swizzled)
    short* kbuf2 = smem;                             // [240][40] QK rounds
    short* qbuf2 = smem + QB2_OFF;                   // [180][40] QK rounds
    short* vbuf  = smem;                             // [240][32]sw V rounds
    short* o1b   = smem + O1_OFF;                    // [180][64]sw V/conv
    float* tb2   = (float*)smem;                     // [64][132] epilogue

    const int t    = threadIdx.x;
    const int w    = t >> 6;
    const int lane = t & 63;
    const int n16  = lane & 15;
    const int quad = lane >> 4;

    // XCD-chunk swizzle (round-2 verified: FETCH 260->58 MB): XCD k owns a
    // contiguous chunk of tiles. 2048 % 8 == 0 -> bijective.
    const int d   = blockIdx.x + (blockIdx.y << 4) + (blockIdx.z << 9);
    const int nn  = ((d & 7) << 8) | (d >> 3);
    const int b   = nn >> 9;
    const int rem = nn & 511;
    const int gy0 = (rem >> 4) * TH;
    const int gx0 = (rem & 15) * TW;
    const float* xb = x + (size_t)b * CHW;

    // ---- phase X: stage x halo into LDS bf16. Channel-PAIR packed b32
    // writes + granule swizzle (round-4 verified: conflicts 1.87e7 -> 6.7e6).
    for (int slot = t; slot < 32*12*6; slot += 256) {
        int s6 = slot % 6, y = (slot / 6) % 12, c2 = slot / 72;
        int c  = c2 * 2;
        int gy = gy0 - 2 + y;
        int gxb = gx0 - 4 + s6*4;
        float v0[4], v1[4];
        bool gyok = (unsigned)gy < HH;
        if (gyok && gxb >= 0 && gxb + 3 < WW) {
            float4_ f0 = *(const float4_*)(xb + (size_t)c*HW + gy*WW + gxb);
            float4_ f1 = *(const float4_*)(xb + (size_t)(c+1)*HW + gy*WW + gxb);
            #pragma unroll
            for (int i = 0; i < 4; ++i) { v0[i] = f0[i]; v1[i] = f1[i]; }
        } else {
            #pragma unroll
            for (int i = 0; i < 4; ++i) {
                int gx = gxb + i;
                bool ok = gyok && (unsigned)gx < WW;
                v0[i] = ok ? xb[(size_t)c*HW + gy*WW + gx] : 0.f;
                v1[i] = ok ? xb[(size_t)(c+1)*HW + gy*WW + gx] : 0.f;
            }
        }
        #pragma unroll
        for (int i = 0; i < 4; ++i) {
            int pxc = s6*4 + i - 2;
            if ((unsigned)pxc < XPW)
                *(unsigned*)&xls[xls_idx(y*XPW + pxc, c)] = pack2(v0[i], v1[i]);
        }
    }
    __syncthreads();

    // per-tile OOB mask: bit i -> pixel (w*4+i)*16 + n16 (uniform in quad/r
    // under the swapped-operand C layout)
    unsigned okb = 0;
    #pragma unroll
    for (int i = 0; i < 4; ++i) {
        int p = (w*4 + i)*16 + n16;
        if (p < NXP) {
            int gy = gy0 - 2 + p / XPW, gx = gx0 - 2 + p % XPW;
            if (((unsigned)gy < HH) && ((unsigned)gx < WW))
                okb |= 1u << i;
        }
    }

    // ---- A-frags (swizzled reads, static-indexed) + residual capture
    short8 afr[4][2];
    #pragma unroll
    for (int i = 0; i < 4; ++i) {
        int p = (w*4 + i)*16 + n16;
        int pr = (p < NXP) ? p : 0;        // clamped dummy for wave3/i3
        #pragma unroll
        for (int ks = 0; ks < 2; ++ks)
            afr[i][ks] = *(const short8*)&xls[xls_idx(pr, ks*32 + quad*8)];
    }
    // per-thread attention pixel
    const int op_py = t / OPW, op_px = t % OPW;
    const int ogy = gy0 - 1 + op_py, ogx = gx0 - 1 + op_px;
    const bool oin = (t < NOP) && ((unsigned)ogy < HH) && ((unsigned)ogx < WW);
    const int xpix = (op_py + 1)*XPW + (op_px + 1);
    short8 resi[8];
    if (t < NOP) {
        #pragma unroll
        for (int g = 0; g < 8; ++g)
            resi[g] = *(const short8*)&xls[xls_idx(xpix, g*8)];
    }
    __syncthreads();   // xls dead; k/q regions may now be written

    // B-fragment loader (global, L2-resident 24 KB)
    auto wload = [&](int sec, int q16, int ks) -> short8 {
        return *(const short8*)&wsq[(((sec*4 + q16)*2 + ks) << 9) + lane*8];
    };
    // 4 biases for channels base+quad*4+{0..3}
    auto bload = [&](int base) -> float4_ {
        return *(const float4_*)&bqkv[base + quad*4];
    };
    // gemm 16 out-ch, swapped operands: D[ch=quad*4+r][pix=n16]; one b64
    // store of 4 consecutive channels per tile
    auto gemm_k = [&](short8 w0, short8 w1, float4_ b4, int coff) {
        __builtin_amdgcn_s_setprio(1);
        #pragma unroll
        for (int i = 0; i < 4; ++i) {
            int p = (w*4 + i)*16 + n16;
            float4_ c = {0.f, 0.f, 0.f, 0.f};
            c = __builtin_amdgcn_mfma_f32_16x16x32_bf16(w0, afr[i][0], c, 0, 0, 0);
            c = __builtin_amdgcn_mfma_f32_16x16x32_bf16(w1, afr[i][1], c, 0, 0, 0);
            if (p < NXP) {
                bool ok = (okb >> i) & 1u;
                short4_ s;
                #pragma unroll
                for (int r = 0; r < 4; ++r) s[r] = ok ? f2bs(c[r] + b4[r]) : (short)0;
                *(short4_*)&kbuf2[p*KQ2 + coff + quad*4] = s;
            }
        }
        __builtin_amdgcn_s_setprio(0);
    };
    auto gemm_v = [&](short8 w0, short8 w1, float4_ b4, int coff) {
        __builtin_amdgcn_s_setprio(1);
        #pragma unroll
        for (int i = 0; i < 4; ++i) {
            int p = (w*4 + i)*16 + n16;
            float4_ c = {0.f, 0.f, 0.f, 0.f};
            c = __builtin_amdgcn_mfma_f32_16x16x32_bf16(w0, afr[i][0], c, 0, 0, 0);
            c = __builtin_amdgcn_mfma_f32_16x16x32_bf16(w1, afr[i][1], c, 0, 0, 0);
            if (p < NXP) {
                bool ok = (okb >> i) & 1u;
                short4_ s;
                #pragma unroll
                for (int r = 0; r < 4; ++r) s[r] = ok ? f2bs(c[r] + b4[r]) : (short)0;
                int cc = coff + quad*4;
                int idx = p*VS + ((((cc >> 3) ^ vswz(p)) & 3) << 3) + (cc & 7);
                *(short4_*)&vbuf[idx] = s;
            }
        }
        __builtin_amdgcn_s_setprio(0);
    };
    auto gemm_q = [&](short8 w0, short8 w1, float4_ b4, int coff) {
        __builtin_amdgcn_s_setprio(1);
        #pragma unroll
        for (int i = 0; i < 4; ++i) {
            int p = (w*4 + i)*16 + n16;
            float4_ c = {0.f, 0.f, 0.f, 0.f};
            c = __builtin_amdgcn_mfma_f32_16x16x32_bf16(w0, afr[i][0], c, 0, 0, 0);
            c = __builtin_amdgcn_mfma_f32_16x16x32_bf16(w1, afr[i][1], c, 0, 0, 0);
            int py = p / XPW, px = p % XPW;
            if ((unsigned)(py - 1) < (unsigned)OPH &&
                (unsigned)(px - 1) < (unsigned)OPW) {
                int op = (py - 1)*OPW + (px - 1);
                short4_ s;
                #pragma unroll
                for (int r = 0; r < 4; ++r) s[r] = f2bs(c[r] + b4[r]);
                *(short4_*)&qbuf2[op*KQ2 + coff + quad*4] = s;
            }
        }
        __builtin_amdgcn_s_setprio(0);
    };

    // ---- QK: 2 rounds x 32 channels
    float dots[9];
    #pragma unroll
    for (int n2 = 0; n2 < 9; ++n2) dots[n2] = 0.f;

    short8 pw0 = wload(0,0,0), pw1 = wload(0,0,1);   // prefetched first pair

    #pragma unroll
    for (int rr = 0; rr < 2; ++rr) {
        {
            short8 b0 = wload(0, 2*rr+1, 0), b1 = wload(0, 2*rr+1, 1);
            // q biases carry the folded 1/8 scale (weights scaled in prep)
            gemm_q(pw0, pw1, bload((2*rr)*16) * 0.125f, 0);
            gemm_q(b0,  b1,  bload((2*rr+1)*16) * 0.125f, 16);
            short8 c0 = wload(1, 2*rr,   0), c1 = wload(1, 2*rr,   1);
            short8 d0 = wload(1, 2*rr+1, 0), d1 = wload(1, 2*rr+1, 1);
            gemm_k(c0, c1, bload(64 + (2*rr)*16),  0);
            gemm_k(d0, d1, bload(64 + (2*rr+1)*16), 16);
        }
        __syncthreads();
        // prefetch next phase's first pair AFTER the barrier (drains at the
        // NEXT barrier; compiler emits vmcnt(0) at every s_barrier)
        if (rr == 0) { pw0 = wload(0, 2, 0); pw1 = wload(0, 2, 1); }
        else         { pw0 = wload(2, 0, 0); pw1 = wload(2, 0, 1); }
        if (oin) {
            uint4_ qa = *(const uint4_*)&qbuf2[t*KQ2];
            uint4_ qb = *(const uint4_*)&qbuf2[t*KQ2 + 8];
            uint4_ qc = *(const uint4_*)&qbuf2[t*KQ2 + 16];
            uint4_ qd = *(const uint4_*)&qbuf2[t*KQ2 + 24];
            #pragma unroll
            for (int n2 = 0; n2 < 9; ++n2) {
                int np = xpix + (n2/3 - 1)*XPW + (n2%3 - 1);
                uint4_ ka = *(const uint4_*)&kbuf2[np*KQ2];
                uint4_ kb = *(const uint4_*)&kbuf2[np*KQ2 + 8];
                uint4_ kc = *(const uint4_*)&kbuf2[np*KQ2 + 16];
                uint4_ kd = *(const uint4_*)&kbuf2[np*KQ2 + 24];
                // 4 independent 4-deep chains (round-8)
                float sA = dots[n2], sB = 0.f, sC = 0.f, sD = 0.f;
                #pragma unroll
                for (int j = 0; j < 4; ++j) sA = dot2acc(qa[j], ka[j], sA);
                #pragma unroll
                for (int j = 0; j < 4; ++j) sB = dot2acc(qb[j], kb[j], sB);
                #pragma unroll
                for (int j = 0; j < 4; ++j) sC = dot2acc(qc[j], kc[j], sC);
                #pragma unroll
                for (int j = 0; j < 4; ++j) sD = dot2acc(qd[j], kd[j], sD);
                dots[n2] = (sA + sB) + (sC + sD);
            }
        }
        __syncthreads();
    }

    // ---- softmax (registers; scale already folded into q)
    float attn[9];
    if (oin) {
        float mx = -1e30f;
        #pragma unroll
        for (int n2 = 0; n2 < 9; ++n2) mx = fmaxf(mx, dots[n2]);
        float se = 0.f;
        #pragma unroll
        for (int n2 = 0; n2 < 9; ++n2) { attn[n2] = __expf(dots[n2] - mx); se += attn[n2]; }
        float inv = 1.f / se;
        #pragma unroll
        for (int n2 = 0; n2 < 9; ++n2) attn[n2] *= inv;
    }

    // PV aggregation for one 32-ch group
    auto pv_round = [&](int rr2) {
        if (t < NOP) {
            #pragma unroll
            for (int h2 = 0; h2 < 2; ++h2) {
                const int kg = rr2*2 + h2;           // 16-ch group 0..3
                short8 s0, s1;
                if (oin) {
                    float o1[16];
                    uint4_ r0 = __builtin_bit_cast(uint4_, resi[kg*2]);
                    uint4_ r1 = __builtin_bit_cast(uint4_, resi[kg*2 + 1]);
                    #pragma unroll
                    for (int j = 0; j < 4; ++j) {
                        o1[2*j]     = blo(r0[j]); o1[2*j + 1]     = bhi(r0[j]);
                        o1[8 + 2*j] = blo(r1[j]); o1[8 + 2*j + 1] = bhi(r1[j]);
                    }
                    #pragma unroll
                    for (int n2 = 0; n2 < 9; ++n2) {
                        float a = attn[n2];
                        int np = xpix + (n2/3 - 1)*XPW + (n2%3 - 1);
                        int sw = vswz(np);
                        uint4_ va = *(const uint4_*)&vbuf[np*VS + (((h2*2)   ^ sw) << 3)];
                        uint4_ vb = *(const uint4_*)&vbuf[np*VS + (((h2*2+1) ^ sw) << 3)];
                        #pragma unroll
                        for (int j = 0; j < 4; ++j) {
                            o1[2*j]         += a * blo(va[j]);
                            o1[2*j + 1]     += a * bhi(va[j]);
                            o1[8 + 2*j]     += a * blo(vb[j]);
                            o1[8 + 2*j + 1] += a * bhi(vb[j]);
                        }
                    }
                    #pragma unroll
                    for (int j = 0; j < 8; ++j) {
                        s0[j] = f2bs(o1[j]);
                        s1[j] = f2bs(o1[8 + j]);
                    }
                } else {
                    #pragma unroll
                    for (int j = 0; j < 8; ++j) { s0[j] = 0; s1[j] = 0; }  // conv zero-pad
                }
                *(short8*)&o1b[o1_idx(t, kg*16)]     = s0;
                *(short8*)&o1b[o1_idx(t, kg*16 + 8)] = s1;
            }
        }
    };

    // ---- V round 0 (ch 0-31)
    {
        short8 b2 = wload(2, 1, 0), b3 = wload(2, 1, 1);
        gemm_v(pw0, pw1, bload(128), 0);
        gemm_v(b2,  b3,  bload(128 + 16), 16);
    }
    __syncthreads();
    pw0 = wload(2, 2, 0); pw1 = wload(2, 2, 1);
    pv_round(0);
    __syncthreads();

    // ---- V round 1 (ch 32-63)
    {
        short8 b2 = wload(2, 3, 0), b3 = wload(2, 3, 1);
        gemm_v(pw0, pw1, bload(128 + 32), 0);
        gemm_v(b2,  b3,  bload(128 + 48), 16);
    }
    __syncthreads();
    // conv ks=0 weight preload: issued here, latency hides under PV round 1;
    // the vmcnt(0) drain at the next barrier guarantees arrival. +16 VGPR
    // transient (budget: 84+16 <= 128).
    short8 cw[4];
    #pragma unroll
    for (int nt = 0; nt < 4; ++nt)
        cw[nt] = *(const short8*)&wsm[((nt*18) << 9) + lane*8];
    pv_round(1);
    __syncthreads();

    // ---- 3x3 conv 64->64 as one MFMA burst (K=576 tap-major), B from ws.
    // Depth-1 weight rotation: ks+1's 4 fragments load while ks's 8 MFMAs
    // run. R7 falsified the old "rotation spilled" claim (R5's VGPR never
    // moved; its regression was the concurrent layout change). Watch
    // VGPR_Count <= 128.
    float4_ acc[4][2];
    #pragma unroll
    for (int nt = 0; nt < 4; ++nt) {
        acc[nt][0] = (float4_){0.f,0.f,0.f,0.f};
        acc[nt][1] = (float4_){0.f,0.f,0.f,0.f};
    }
    const int mtc0 = w*2, mtc1 = w*2 + 1;
    for (int ks = 0; ks < 18; ++ks) {
        short8 nw[4];
        if (ks < 17) {
            #pragma unroll
            for (int nt = 0; nt < 4; ++nt)
                nw[nt] = *(const short8*)&wsm[((nt*18 + ks + 1) << 9) + lane*8];
        }
        int tap = ks >> 1;
        int dy = tap/3 - 1, dx = tap%3 - 1;
        int cin0 = (ks & 1)*32 + quad*8;
        int pixA = (mtc0 + 1 + dy)*OPW + (n16 + 1 + dx);
        int pixB = (mtc1 + 1 + dy)*OPW + (n16 + 1 + dx);
        short8 a0 = *(const short8*)&o1b[o1_idx(pixA, cin0)];
        short8 a1 = *(const short8*)&o1b[o1_idx(pixB, cin0)];
        __builtin_amdgcn_s_setprio(1);
        #pragma unroll
        for (int nt = 0; nt < 4; ++nt) {
            acc[nt][0] = __builtin_amdgcn_mfma_f32_16x16x32_bf16(a0, cw[nt], acc[nt][0], 0, 0, 0);
            acc[nt][1] = __builtin_amdgcn_mfma_f32_16x16x32_bf16(a1, cw[nt], acc[nt][1], 0, 0, 0);
        }
        __builtin_amdgcn_s_setprio(0);
        if (ks < 17) {
            #pragma unroll
            for (int nt = 0; nt < 4; ++nt) cw[nt] = nw[nt];
        }
    }
    __syncthreads();   // tb2 overlaps vbuf/o1b: all conv reads must land

    // ---- epilogue: single flipped tbuf [ch][132], all-b128 (round-10)
    #pragma unroll
    for (int nt = 0; nt < 4; ++nt)
        #pragma unroll
        for (int h = 0; h < 2; ++h) {
            float4_ rv;
            #pragma unroll
            for (int r = 0; r < 4; ++r) rv[r] = fmaxf(acc[nt][h][r], 0.f);
            *(float4_*)&tb2[(nt*16 + n16)*TBS + (w*2 + h)*16 + quad*4] = rv;
        }
    __syncthreads();
    #pragma unroll
    for (int k = 0; k < 8; ++k) {
        int unit = t + k*256;                  // 2048 units: ch(64) y(8) xg(4)
        int ch = unit >> 5, y = (unit >> 2) & 7, xg = unit & 3;
        float4_ v = *(const float4_*)&tb2[ch*TBS + y*16 + xg*4];
        *(float4_*)(out + (size_t)b*CHW + (size_t)ch*HW
                    + (size_t)(gy0 + y)*WW + (gx0 + xg*4)) = v;
    }
}

extern "C" void kernel_launch(void* const* d_in, const int* in_sizes, int n_in,
                              void* d_out, int out_size, void* d_ws, size_t ws_size,
                              hipStream_t stream) {
    const float* x    = (const float*)d_in[0];
    const float* wqkv = (const float*)d_in[1];
    const float* bqkv = (const float*)d_in[2];
    const float* wmlp = (const float*)d_in[3];
    float* outp = (float*)d_out;

    short* wsq = (short*)d_ws;                      // 24576 B
    short* wsm = wsq + WSQ_SHORTS;                  // 73728 B  (total 98304 B)

    prep_pack<<<128, 256, 0, stream>>>(wqkv, wmlp, wsq, wsm);

    dim3 grid(WW/TW, HH/TH, 4);
    fused_mfma<<<grid, 256, 0, stream>>>(x, wsq, bqkv, wsm, outp);
}